// Round 5
// baseline (1959.848 us; speedup 1.0000x reference)
//
#include <hip/hip_runtime.h>
#include <hip/hip_bf16.h>
#include <cstdint>

typedef __bf16 bf16;
typedef __bf16 bf16x8 __attribute__((ext_vector_type(8)));
typedef __bf16 bf16x4 __attribute__((ext_vector_type(4)));
typedef float f32x4 __attribute__((ext_vector_type(4)));

#define DEV __device__ __forceinline__

DEV float wred_sum(float v) {
#pragma unroll
  for (int off = 32; off > 0; off >>= 1) v += __shfl_xor(v, off, 64);
  return v;
}
DEV float wred_max(float v) {
#pragma unroll
  for (int off = 32; off > 0; off >>= 1) v = fmaxf(v, __shfl_xor(v, off, 64));
  return v;
}

// ---------------- weight convert + transpose: in [K,N] f32 -> out [N,K] bf16
__global__ void convT_kernel(const float* __restrict__ in, bf16* __restrict__ out,
                             int K, int N) {
  __shared__ float t[32][33];
  const int n0 = blockIdx.x * 32, k0 = blockIdx.y * 32;
  const int tx = threadIdx.x & 31, ty = threadIdx.x >> 5;  // 32x8
#pragma unroll
  for (int i = 0; i < 4; i++)
    t[ty + 8 * i][tx] = in[(long)(k0 + ty + 8 * i) * N + n0 + tx];
  __syncthreads();
#pragma unroll
  for (int i = 0; i < 4; i++)
    out[(long)(n0 + ty + 8 * i) * K + k0 + tx] = (bf16)t[tx][ty + 8 * i];
}

// ---------------- layernorm (row=1024) f32 -> bf16
__global__ void ln_bf16_kernel(const float* __restrict__ x, const float* __restrict__ g,
                               const float* __restrict__ be, bf16* __restrict__ out) {
  const long row = blockIdx.x;
  const int tid = threadIdx.x;  // 256
  const float4 v = ((const float4*)(x + row * 1024))[tid];
  float s = v.x + v.y + v.z + v.w;
  float s2 = v.x * v.x + v.y * v.y + v.z * v.z + v.w * v.w;
  __shared__ float rs_[4], rs2_[4];
  s = wred_sum(s);
  s2 = wred_sum(s2);
  const int wave = tid >> 6, lane = tid & 63;
  if (lane == 0) { rs_[wave] = s; rs2_[wave] = s2; }
  __syncthreads();
  s = rs_[0] + rs_[1] + rs_[2] + rs_[3];
  s2 = rs2_[0] + rs2_[1] + rs2_[2] + rs2_[3];
  const float mu = s * (1.0f / 1024.0f);
  const float var = s2 * (1.0f / 1024.0f) - mu * mu;
  const float rstd = rsqrtf(var + 1e-5f);
  const float4 gg = ((const float4*)g)[tid];
  const float4 bb = ((const float4*)be)[tid];
  bf16x4 o;
  o[0] = (bf16)((v.x - mu) * rstd * gg.x + bb.x);
  o[1] = (bf16)((v.y - mu) * rstd * gg.y + bb.y);
  o[2] = (bf16)((v.z - mu) * rstd * gg.z + bb.z);
  o[3] = (bf16)((v.w - mu) * rstd * gg.w + bb.w);
  *(bf16x4*)(out + row * 1024 + tid * 4) = o;
}

// ---------------- softmax over rows of 4096, in-place bf16
__global__ void softmax_kernel(bf16* __restrict__ p) {
  const long row = blockIdx.x;
  bf16* pr = p + row * 4096;
  const int tid = threadIdx.x;  // 256, 16 elems each
  bf16x8 a = *(const bf16x8*)(pr + tid * 16);
  bf16x8 b = *(const bf16x8*)(pr + tid * 16 + 8);
  float v[16];
#pragma unroll
  for (int i = 0; i < 8; i++) { v[i] = (float)a[i]; v[8 + i] = (float)b[i]; }
  float mx = -1e30f;
#pragma unroll
  for (int i = 0; i < 16; i++) mx = fmaxf(mx, v[i]);
  __shared__ float red1[4], red2[4];
  mx = wred_max(mx);
  const int wave = tid >> 6, lane = tid & 63;
  if (lane == 0) red1[wave] = mx;
  __syncthreads();
  mx = fmaxf(fmaxf(red1[0], red1[1]), fmaxf(red1[2], red1[3]));
  float s = 0.0f;
#pragma unroll
  for (int i = 0; i < 16; i++) { v[i] = __expf(v[i] - mx); s += v[i]; }
  s = wred_sum(s);
  if (lane == 0) red2[wave] = s;
  __syncthreads();
  s = red2[0] + red2[1] + red2[2] + red2[3];
  const float inv = 1.0f / s;
#pragma unroll
  for (int i = 0; i < 8; i++) { a[i] = (bf16)(v[i] * inv); b[i] = (bf16)(v[8 + i] * inv); }
  *(bf16x8*)(pr + tid * 16) = a;
  *(bf16x8*)(pr + tid * 16 + 8) = b;
}

// ---------------- NT GEMM: C[m,n] = alpha * sum_k A[m,k]*B[n,k] (+bias[n]) (+resid)
// m97 structure: 128x128 tile, BK=32, 4 waves, 16x16x32 MFMA, global_load_lds w=16.
// Staging: tile is 8KB = 512 x 16B chunks; 256 threads => TWO issues per buffer:
// rows srow and srow+64, LDS dests tid*16B and (256+tid)*16B (wave-uniform+lane*16B).
enum { EPI_BF16 = 0, EPI_BF16T = 1, EPI_GELU = 2, EPI_F32RES = 3 };

template <int EPI>
__global__ __launch_bounds__(256)
void gemm_nt(const bf16* __restrict__ A, const bf16* __restrict__ B,
             const float* __restrict__ bias, const float* resid,
             void* Cout, int M, int N, int K,
             int lda, int ldb, int ldc, float alpha) {
  __shared__ __align__(16) bf16 sA[128 * 32];
  __shared__ __align__(16) bf16 sB[128 * 32];
  const int tid = threadIdx.x;
  const int wave = tid >> 6;
  const int lane = tid & 63;
  const int q = lane >> 4;
  const int r16 = lane & 15;
  const int wm = (wave >> 1) * 64;
  const int wn = (wave & 1) * 64;
  const long m0 = (long)blockIdx.y * 128;
  const long n0 = (long)blockIdx.x * 128;
  const int srow = tid >> 2;          // 0..63 (4 threads/row, 16B each)
  const int scol = (tid & 3) * 8;
  const bf16* ag0 = A + (m0 + srow) * (long)lda + scol;
  const bf16* ag1 = ag0 + 64 * (long)lda;          // rows 64..127
  const bf16* bg0 = B + (n0 + srow) * (long)ldb + scol;
  const bf16* bg1 = bg0 + 64 * (long)ldb;
  bf16* la0 = sA + tid * 8;            // elements (tid)*8   -> rows 0..63
  bf16* la1 = sA + (256 + tid) * 8;    // elements (256+tid)*8 -> rows 64..127
  bf16* lb0 = sB + tid * 8;
  bf16* lb1 = sB + (256 + tid) * 8;
  f32x4 acc[4][4] = {};
  for (int k0 = 0; k0 < K; k0 += 32) {
    __builtin_amdgcn_global_load_lds(
        (const __attribute__((address_space(1))) void*)(ag0 + k0),
        (__attribute__((address_space(3))) void*)la0, 16, 0, 0);
    __builtin_amdgcn_global_load_lds(
        (const __attribute__((address_space(1))) void*)(ag1 + k0),
        (__attribute__((address_space(3))) void*)la1, 16, 0, 0);
    __builtin_amdgcn_global_load_lds(
        (const __attribute__((address_space(1))) void*)(bg0 + k0),
        (__attribute__((address_space(3))) void*)lb0, 16, 0, 0);
    __builtin_amdgcn_global_load_lds(
        (const __attribute__((address_space(1))) void*)(bg1 + k0),
        (__attribute__((address_space(3))) void*)lb1, 16, 0, 0);
    __syncthreads();  // drains vmcnt before barrier
    bf16x8 af[4], bfr[4];
#pragma unroll
    for (int i = 0; i < 4; i++)
      af[i] = *(const bf16x8*)(sA + (wm + i * 16 + r16) * 32 + q * 8);
#pragma unroll
    for (int j = 0; j < 4; j++)
      bfr[j] = *(const bf16x8*)(sB + (wn + j * 16 + r16) * 32 + q * 8);
#pragma unroll
    for (int i = 0; i < 4; i++)
#pragma unroll
      for (int j = 0; j < 4; j++)
        acc[i][j] = __builtin_amdgcn_mfma_f32_16x16x32_bf16(af[i], bfr[j], acc[i][j], 0, 0, 0);
    __syncthreads();
  }
#pragma unroll
  for (int j = 0; j < 4; j++) {
    const long col = n0 + wn + j * 16 + r16;
    const float bv = bias ? bias[col] : 0.0f;
#pragma unroll
    for (int i = 0; i < 4; i++) {
#pragma unroll
      for (int r = 0; r < 4; r++) {
        const long row = m0 + wm + i * 16 + q * 4 + r;
        float v = acc[i][j][r] * alpha + bv;
        if (EPI == EPI_BF16) {
          ((bf16*)Cout)[row * (long)ldc + col] = (bf16)v;
        } else if (EPI == EPI_BF16T) {
          ((bf16*)Cout)[col * (long)ldc + row] = (bf16)v;
        } else if (EPI == EPI_GELU) {
          const float gl = 0.5f * v * (1.0f + erff(v * 0.70710678118654752f));
          ((bf16*)Cout)[row * (long)ldc + col] = (bf16)gl;
        } else {  // EPI_F32RES (in-place safe: each idx owned by one thread)
          const long idx = row * (long)ldc + col;
          ((float*)Cout)[idx] = v + resid[idx];
        }
      }
    }
  }
}

extern "C" void kernel_launch(void* const* d_in, const int* in_sizes, int n_in,
                              void* d_out, int out_size, void* d_ws, size_t ws_size,
                              hipStream_t stream) {
  const float* x  = (const float*)d_in[0];
  const float* wq = (const float*)d_in[1];
  const float* bq = (const float*)d_in[2];
  const float* wk = (const float*)d_in[3];
  const float* bk = (const float*)d_in[4];
  const float* wv = (const float*)d_in[5];
  const float* bv = (const float*)d_in[6];
  const float* wo = (const float*)d_in[7];
  const float* bo = (const float*)d_in[8];
  const float* w1 = (const float*)d_in[9];
  const float* b1 = (const float*)d_in[10];
  const float* w2 = (const float*)d_in[11];
  const float* b2 = (const float*)d_in[12];
  const float* g1 = (const float*)d_in[13];
  const float* be1 = (const float*)d_in[14];
  const float* g2 = (const float*)d_in[15];
  const float* be2 = (const float*)d_in[16];

  const long MB = 1 << 20;
  char* ws = (char*)d_ws;
  char* ob = (char*)d_out;
  // bf16 [N,K] weights, always at the bottom of ws (24 MB total)
  bf16* WQ = (bf16*)(ws + 0 * MB);
  bf16* WK = (bf16*)(ws + 2 * MB);
  bf16* WV = (bf16*)(ws + 4 * MB);
  bf16* WO = (bf16*)(ws + 6 * MB);
  bf16* W1 = (bf16*)(ws + 8 * MB);    // [4096,1024]
  bf16* W2 = (bf16*)(ws + 16 * MB);   // [1024,4096]
  float* OUT = (float*)d_out;
  const dim3 blk(256);

  // 1. weight convert+transpose (both plans)
  convT_kernel<<<dim3(32, 32), blk, 0, stream>>>(wq, WQ, 1024, 1024);
  convT_kernel<<<dim3(32, 32), blk, 0, stream>>>(wk, WK, 1024, 1024);
  convT_kernel<<<dim3(32, 32), blk, 0, stream>>>(wv, WV, 1024, 1024);
  convT_kernel<<<dim3(32, 32), blk, 0, stream>>>(wo, WO, 1024, 1024);
  convT_kernel<<<dim3(128, 32), blk, 0, stream>>>(w1, W1, 1024, 4096);
  convT_kernel<<<dim3(32, 128), blk, 0, stream>>>(w2, W2, 4096, 1024);

  if (ws_size >= (size_t)(56 * MB)) {
    // ================= PLAN B: ws peak 56 MB =================
    // ws:   0-24 weights | 24-56 A (bf16 [16384,1024]); FFN: 0-8 H2_m, 24-56 F_m
    // dout: 0-32 P | 32-40 Qb | 40-48 Kb | 48-56 Vt | 56-64 Hb   (all dead pre-X1)
    bf16* Ab = (bf16*)(ws + 24 * MB);
    bf16* P  = (bf16*)(ob + 0 * MB);
    bf16* Qb = (bf16*)(ob + 32 * MB);
    bf16* Kb = (bf16*)(ob + 40 * MB);
    bf16* Vt = (bf16*)(ob + 48 * MB);
    bf16* Hb = (bf16*)(ob + 56 * MB);
    for (int z = 0; z < 4; z++) {
      const long zo = (long)z * 4096 * 1024;
      ln_bf16_kernel<<<4096, blk, 0, stream>>>(x + zo, g1, be1, Hb);
      gemm_nt<EPI_BF16><<<dim3(8, 32), blk, 0, stream>>>(
          Hb, WQ, bq, nullptr, Qb, 4096, 1024, 1024, 1024, 1024, 1024, 1.0f);
      gemm_nt<EPI_BF16><<<dim3(8, 32), blk, 0, stream>>>(
          Hb, WK, bk, nullptr, Kb, 4096, 1024, 1024, 1024, 1024, 1024, 1.0f);
      gemm_nt<EPI_BF16T><<<dim3(8, 32), blk, 0, stream>>>(
          Hb, WV, bv, nullptr, Vt, 4096, 1024, 1024, 1024, 1024, 4096, 1.0f);
      gemm_nt<EPI_BF16><<<dim3(32, 32), blk, 0, stream>>>(
          Qb, Kb, nullptr, nullptr, P, 4096, 4096, 1024, 1024, 1024, 4096, 1.0f / 32.0f);
      softmax_kernel<<<4096, blk, 0, stream>>>(P);
      gemm_nt<EPI_BF16><<<dim3(8, 32), blk, 0, stream>>>(
          P, Vt, nullptr, nullptr, Ab + zo, 4096, 1024, 4096, 4096, 4096, 1024, 1.0f);
    }
    // X1 = x + A @ WO^T + bo  -> d_out (all scratch dead)
    gemm_nt<EPI_F32RES><<<dim3(8, 128), blk, 0, stream>>>(
        Ab, WO, bo, x, OUT, 16384, 1024, 1024, 1024, 1024, 1024, 1.0f);
    // FFN, M-chunks of 4096 rows; H2_m over dead WQ..WO, F_m over dead A
    bf16* H2m = (bf16*)(ws + 0 * MB);   // 8 MB
    bf16* Fm  = (bf16*)(ws + 24 * MB);  // 32 MB
    for (int mc = 0; mc < 4; mc++) {
      const long ro = (long)mc * 4096 * 1024;
      ln_bf16_kernel<<<4096, blk, 0, stream>>>(OUT + ro, g2, be2, H2m);
      gemm_nt<EPI_GELU><<<dim3(32, 32), blk, 0, stream>>>(
          H2m, W1, b1, nullptr, Fm, 4096, 4096, 1024, 1024, 1024, 4096, 1.0f);
      gemm_nt<EPI_F32RES><<<dim3(8, 32), blk, 0, stream>>>(
          Fm, W2, b2, OUT + ro, OUT + ro, 4096, 1024, 4096, 4096, 4096, 1024, 1.0f);
    }
  } else {
    // ================= PLAN C: ws peak 32 MB =================
    // ws:   0-24 weights | 24-32 spill slot S
    // dout: 0-8 Qb | 8-16 Kb | 16-24 Vt | 24-32 Hb/Pc | 32-64 A (bf16 [16384,1024])
    bf16* S  = (bf16*)(ws + 24 * MB);
    bf16* Qb = (bf16*)(ob + 0 * MB);
    bf16* Kb = (bf16*)(ob + 8 * MB);
    bf16* Vt = (bf16*)(ob + 16 * MB);
    bf16* Hb = (bf16*)(ob + 24 * MB);
    bf16* Pc = Hb;                      // reuse after QKV done
    bf16* Af = (bf16*)(ob + 32 * MB);
    for (int z = 0; z < 4; z++) {
      const long zo = (long)z * 4096 * 1024;
      ln_bf16_kernel<<<4096, blk, 0, stream>>>(x + zo, g1, be1, Hb);
      gemm_nt<EPI_BF16><<<dim3(8, 32), blk, 0, stream>>>(
          Hb, WQ, bq, nullptr, Qb, 4096, 1024, 1024, 1024, 1024, 1024, 1.0f);
      gemm_nt<EPI_BF16><<<dim3(8, 32), blk, 0, stream>>>(
          Hb, WK, bk, nullptr, Kb, 4096, 1024, 1024, 1024, 1024, 1024, 1.0f);
      gemm_nt<EPI_BF16T><<<dim3(8, 32), blk, 0, stream>>>(
          Hb, WV, bv, nullptr, Vt, 4096, 1024, 1024, 1024, 1024, 4096, 1.0f);
      for (int qc = 0; qc < 4; qc++) {
        gemm_nt<EPI_BF16><<<dim3(32, 8), blk, 0, stream>>>(
            Qb + (long)qc * 1024 * 1024, Kb, nullptr, nullptr, Pc,
            1024, 4096, 1024, 1024, 1024, 4096, 1.0f / 32.0f);
        softmax_kernel<<<1024, blk, 0, stream>>>(Pc);
        gemm_nt<EPI_BF16><<<dim3(8, 8), blk, 0, stream>>>(
            Pc, Vt, nullptr, nullptr, Af + zo + (long)qc * 1024 * 1024,
            1024, 1024, 4096, 4096, 4096, 1024, 1.0f);
      }
    }
    // A_3 -> S so batch-3 O-proj doesn't overlap its own output region
    hipMemcpyAsync(S, Af + 3L * 4096 * 1024, (size_t)(8 * MB),
                   hipMemcpyDeviceToDevice, stream);
    for (int z = 0; z < 4; z++) {
      const long zo = (long)z * 4096 * 1024;
      const bf16* Az = (z == 3) ? S : (Af + zo);
      gemm_nt<EPI_F32RES><<<dim3(8, 32), blk, 0, stream>>>(
          Az, WO, bo, x + zo, OUT + zo, 4096, 1024, 1024, 1024, 1024, 1024, 1.0f);
    }
    // FFN, M-chunks of 1024 rows; H2 over dead WQ region (2 MB), F in S (8 MB)
    bf16* H2c = (bf16*)(ws + 0 * MB);
    for (int mc = 0; mc < 16; mc++) {
      const long ro = (long)mc * 1024 * 1024;
      ln_bf16_kernel<<<1024, blk, 0, stream>>>(OUT + ro, g2, be2, H2c);
      gemm_nt<EPI_GELU><<<dim3(32, 8), blk, 0, stream>>>(
          H2c, W1, b1, nullptr, S, 1024, 4096, 1024, 1024, 1024, 4096, 1.0f);
      gemm_nt<EPI_F32RES><<<dim3(8, 8), blk, 0, stream>>>(
          S, W2, b2, OUT + ro, OUT + ro, 1024, 1024, 4096, 4096, 4096, 1024, 1.0f);
    }
  }
  (void)in_sizes; (void)n_in; (void)out_size;
}

// Round 6
// 1782.335 us; speedup vs baseline: 1.0996x; 1.0996x over previous
//
#include <hip/hip_runtime.h>
#include <hip/hip_bf16.h>
#include <cstdint>

typedef __bf16 bf16;
typedef __bf16 bf16x8 __attribute__((ext_vector_type(8)));
typedef __bf16 bf16x4 __attribute__((ext_vector_type(4)));
typedef float f32x4 __attribute__((ext_vector_type(4)));

#define DEV __device__ __forceinline__

DEV float wred_sum(float v) {
#pragma unroll
  for (int off = 32; off > 0; off >>= 1) v += __shfl_xor(v, off, 64);
  return v;
}
DEV float wred_max(float v) {
#pragma unroll
  for (int off = 32; off > 0; off >>= 1) v = fmaxf(v, __shfl_xor(v, off, 64));
  return v;
}

// ---------------- weight convert + transpose: in [K,N] f32 -> out [N,K] bf16
__global__ void convT_kernel(const float* __restrict__ in, bf16* __restrict__ out,
                             int K, int N) {
  __shared__ float t[32][33];
  const int n0 = blockIdx.x * 32, k0 = blockIdx.y * 32;
  const int tx = threadIdx.x & 31, ty = threadIdx.x >> 5;  // 32x8
#pragma unroll
  for (int i = 0; i < 4; i++)
    t[ty + 8 * i][tx] = in[(long)(k0 + ty + 8 * i) * N + n0 + tx];
  __syncthreads();
#pragma unroll
  for (int i = 0; i < 4; i++)
    out[(long)(n0 + ty + 8 * i) * K + k0 + tx] = (bf16)t[tx][ty + 8 * i];
}

// ---------------- bf16 transpose: in [R,C] (ldin) -> out [C,R] (ldout)
__global__ void transpose_bf16(const bf16* __restrict__ in, bf16* __restrict__ out,
                               int ldin, int ldout) {
  __shared__ bf16 t[32][33];
  const int c0 = blockIdx.x * 32, r0 = blockIdx.y * 32;
  const int tx = threadIdx.x & 31, ty = threadIdx.x >> 5;  // 32x8
#pragma unroll
  for (int i = 0; i < 4; i++)
    t[ty + 8 * i][tx] = in[(long)(r0 + ty + 8 * i) * ldin + c0 + tx];
  __syncthreads();
#pragma unroll
  for (int i = 0; i < 4; i++)
    out[(long)(c0 + ty + 8 * i) * ldout + r0 + tx] = t[tx][ty + 8 * i];
}

// ---------------- layernorm (row=1024) f32 -> bf16
__global__ void ln_bf16_kernel(const float* __restrict__ x, const float* __restrict__ g,
                               const float* __restrict__ be, bf16* __restrict__ out) {
  const long row = blockIdx.x;
  const int tid = threadIdx.x;  // 256
  const float4 v = ((const float4*)(x + row * 1024))[tid];
  float s = v.x + v.y + v.z + v.w;
  float s2 = v.x * v.x + v.y * v.y + v.z * v.z + v.w * v.w;
  __shared__ float rs_[4], rs2_[4];
  s = wred_sum(s);
  s2 = wred_sum(s2);
  const int wave = tid >> 6, lane = tid & 63;
  if (lane == 0) { rs_[wave] = s; rs2_[wave] = s2; }
  __syncthreads();
  s = rs_[0] + rs_[1] + rs_[2] + rs_[3];
  s2 = rs2_[0] + rs2_[1] + rs2_[2] + rs2_[3];
  const float mu = s * (1.0f / 1024.0f);
  const float var = s2 * (1.0f / 1024.0f) - mu * mu;
  const float rstd = rsqrtf(var + 1e-5f);
  const float4 gg = ((const float4*)g)[tid];
  const float4 bb = ((const float4*)be)[tid];
  bf16x4 o;
  o[0] = (bf16)((v.x - mu) * rstd * gg.x + bb.x);
  o[1] = (bf16)((v.y - mu) * rstd * gg.y + bb.y);
  o[2] = (bf16)((v.z - mu) * rstd * gg.z + bb.z);
  o[3] = (bf16)((v.w - mu) * rstd * gg.w + bb.w);
  *(bf16x4*)(out + row * 1024 + tid * 4) = o;
}

// ---------------- softmax over rows of 4096, in-place bf16
__global__ void softmax_kernel(bf16* __restrict__ p) {
  const long row = blockIdx.x;
  bf16* pr = p + row * 4096;
  const int tid = threadIdx.x;  // 256, 16 elems each
  bf16x8 a = *(const bf16x8*)(pr + tid * 16);
  bf16x8 b = *(const bf16x8*)(pr + tid * 16 + 8);
  float v[16];
#pragma unroll
  for (int i = 0; i < 8; i++) { v[i] = (float)a[i]; v[8 + i] = (float)b[i]; }
  float mx = -1e30f;
#pragma unroll
  for (int i = 0; i < 16; i++) mx = fmaxf(mx, v[i]);
  __shared__ float red1[4], red2[4];
  mx = wred_max(mx);
  const int wave = tid >> 6, lane = tid & 63;
  if (lane == 0) red1[wave] = mx;
  __syncthreads();
  mx = fmaxf(fmaxf(red1[0], red1[1]), fmaxf(red1[2], red1[3]));
  float s = 0.0f;
#pragma unroll
  for (int i = 0; i < 16; i++) { v[i] = __expf(v[i] - mx); s += v[i]; }
  s = wred_sum(s);
  if (lane == 0) red2[wave] = s;
  __syncthreads();
  s = red2[0] + red2[1] + red2[2] + red2[3];
  const float inv = 1.0f / s;
#pragma unroll
  for (int i = 0; i < 8; i++) { a[i] = (bf16)(v[i] * inv); b[i] = (bf16)(v[8 + i] * inv); }
  *(bf16x8*)(pr + tid * 16) = a;
  *(bf16x8*)(pr + tid * 16 + 8) = b;
}

// ---------------- NT GEMM: C[m,n] = alpha * sum_k A[m,k]*B[n,k] (+bias[n]) (+resid)
// m97 structure; MFMA operands SWAPPED (mfma(bfr, af)) so the C/D mapping puts a
// lane's 4 acc values on 4 consecutive COLUMNS: m = r16, n = q*4 + reg.
// => vectorized epilogue: bf16x4 / float4 stores, float4 bias/resid loads.
enum { EPI_BF16 = 0, EPI_QKV = 1, EPI_GELU = 2, EPI_F32RES = 3 };

template <int EPI>
__global__ __launch_bounds__(256)
void gemm_nt(const bf16* __restrict__ A, const bf16* __restrict__ B,
             const float* __restrict__ bias, const float* bias2, const float* bias3,
             const float* resid, void* Cout, int M, int N, int K,
             int lda, int ldb, int ldc, float alpha) {
  __shared__ __align__(16) bf16 sA[128 * 32];
  __shared__ __align__(16) bf16 sB[128 * 32];
  const int tid = threadIdx.x;
  const int wave = tid >> 6;
  const int lane = tid & 63;
  const int q = lane >> 4;
  const int r16 = lane & 15;
  const int wm = (wave >> 1) * 64;
  const int wn = (wave & 1) * 64;
  const long m0 = (long)blockIdx.y * 128;
  const long n0 = (long)blockIdx.x * 128;
  const int srow = tid >> 2;          // 0..63 (4 threads/row, 16B each)
  const int scol = (tid & 3) * 8;
  const bf16* ag0 = A + (m0 + srow) * (long)lda + scol;
  const bf16* ag1 = ag0 + 64 * (long)lda;          // rows 64..127
  const bf16* bg0 = B + (n0 + srow) * (long)ldb + scol;
  const bf16* bg1 = bg0 + 64 * (long)ldb;
  bf16* la0 = sA + tid * 8;            // rows 0..63 (wave-uniform + lane*16B)
  bf16* la1 = sA + (256 + tid) * 8;    // rows 64..127
  bf16* lb0 = sB + tid * 8;
  bf16* lb1 = sB + (256 + tid) * 8;
  f32x4 acc[4][4] = {};
  for (int k0 = 0; k0 < K; k0 += 32) {
    __builtin_amdgcn_global_load_lds(
        (const __attribute__((address_space(1))) void*)(ag0 + k0),
        (__attribute__((address_space(3))) void*)la0, 16, 0, 0);
    __builtin_amdgcn_global_load_lds(
        (const __attribute__((address_space(1))) void*)(ag1 + k0),
        (__attribute__((address_space(3))) void*)la1, 16, 0, 0);
    __builtin_amdgcn_global_load_lds(
        (const __attribute__((address_space(1))) void*)(bg0 + k0),
        (__attribute__((address_space(3))) void*)lb0, 16, 0, 0);
    __builtin_amdgcn_global_load_lds(
        (const __attribute__((address_space(1))) void*)(bg1 + k0),
        (__attribute__((address_space(3))) void*)lb1, 16, 0, 0);
    __syncthreads();  // drains vmcnt before barrier
    bf16x8 af[4], bfr[4];
#pragma unroll
    for (int i = 0; i < 4; i++)
      af[i] = *(const bf16x8*)(sA + (wm + i * 16 + r16) * 32 + q * 8);
#pragma unroll
    for (int j = 0; j < 4; j++)
      bfr[j] = *(const bf16x8*)(sB + (wn + j * 16 + r16) * 32 + q * 8);
#pragma unroll
    for (int i = 0; i < 4; i++)
#pragma unroll
      for (int j = 0; j < 4; j++)  // SWAPPED operand order -> transposed C/D map
        acc[i][j] = __builtin_amdgcn_mfma_f32_16x16x32_bf16(bfr[j], af[i], acc[i][j], 0, 0, 0);
    __syncthreads();
  }
#pragma unroll
  for (int i = 0; i < 4; i++) {
    const long row = m0 + wm + i * 16 + r16;  // m
#pragma unroll
    for (int j = 0; j < 4; j++) {
      const int ncol = (int)n0 + wn + j * 16 + q * 4;  // first of 4 consecutive n
      float4 b4 = make_float4(0.f, 0.f, 0.f, 0.f);
      if (EPI == EPI_QKV) {
        const int band = ncol >> 10;  // block-uniform (128 | 1024)
        const float* bsel = band == 0 ? bias : (band == 1 ? bias2 : bias3);
        b4 = *(const float4*)(bsel + (ncol & 1023));
      } else if (bias != nullptr) {
        b4 = *(const float4*)(bias + ncol);
      }
      float v0 = acc[i][j][0] * alpha + b4.x;
      float v1 = acc[i][j][1] * alpha + b4.y;
      float v2 = acc[i][j][2] * alpha + b4.z;
      float v3 = acc[i][j][3] * alpha + b4.w;
      if (EPI == EPI_GELU) {
        v0 = 0.5f * v0 * (1.0f + erff(v0 * 0.70710678118654752f));
        v1 = 0.5f * v1 * (1.0f + erff(v1 * 0.70710678118654752f));
        v2 = 0.5f * v2 * (1.0f + erff(v2 * 0.70710678118654752f));
        v3 = 0.5f * v3 * (1.0f + erff(v3 * 0.70710678118654752f));
      }
      if (EPI == EPI_F32RES) {
        const long idx = row * (long)ldc + ncol;
        const float4 rr = *(const float4*)(resid + idx);
        const float4 o = make_float4(v0 + rr.x, v1 + rr.y, v2 + rr.z, v3 + rr.w);
        *(float4*)((float*)Cout + idx) = o;
      } else {
        bf16x4 o;
        o[0] = (bf16)v0; o[1] = (bf16)v1; o[2] = (bf16)v2; o[3] = (bf16)v3;
        *(bf16x4*)((bf16*)Cout + row * (long)ldc + ncol) = o;
      }
    }
  }
}

extern "C" void kernel_launch(void* const* d_in, const int* in_sizes, int n_in,
                              void* d_out, int out_size, void* d_ws, size_t ws_size,
                              hipStream_t stream) {
  const float* x  = (const float*)d_in[0];
  const float* wq = (const float*)d_in[1];
  const float* bq = (const float*)d_in[2];
  const float* wk = (const float*)d_in[3];
  const float* bk = (const float*)d_in[4];
  const float* wv = (const float*)d_in[5];
  const float* bv = (const float*)d_in[6];
  const float* wo = (const float*)d_in[7];
  const float* bo = (const float*)d_in[8];
  const float* w1 = (const float*)d_in[9];
  const float* b1 = (const float*)d_in[10];
  const float* w2 = (const float*)d_in[11];
  const float* b2 = (const float*)d_in[12];
  const float* g1 = (const float*)d_in[13];
  const float* be1 = (const float*)d_in[14];
  const float* g2 = (const float*)d_in[15];
  const float* be2 = (const float*)d_in[16];

  const long MB = 1 << 20;
  char* ws = (char*)d_ws;
  char* ob = (char*)d_out;
  // ws (peak 56 MB): 0-6 WQKV [3072,1024] | 6-8 WO | 8-16 W1 | 16-24 W2 |
  //                  24-56 H (LN1 out, overwritten per-batch by A) ; FFN: 0-8 H2m, 24-56 Fm
  bf16* WQKV = (bf16*)(ws + 0 * MB);
  bf16* WO   = (bf16*)(ws + 6 * MB);
  bf16* W1   = (bf16*)(ws + 8 * MB);    // [4096,1024]
  bf16* W2   = (bf16*)(ws + 16 * MB);   // [1024,4096]
  bf16* H    = (bf16*)(ws + 24 * MB);   // [16384,1024]; batch z slice becomes A_z
  // d_out (64 MB, dead before X1): 0-32 P | 32-56 QKVb [4096,3072] | 56-64 Vt [1024,4096]
  bf16* P    = (bf16*)(ob + 0 * MB);
  bf16* QKVb = (bf16*)(ob + 32 * MB);
  bf16* Vt   = (bf16*)(ob + 56 * MB);
  float* OUT = (float*)d_out;
  const dim3 blk(256);

  // 1. weight convert+transpose to [N,K] bf16 (QKV concatenated)
  convT_kernel<<<dim3(32, 32), blk, 0, stream>>>(wq, WQKV, 1024, 1024);
  convT_kernel<<<dim3(32, 32), blk, 0, stream>>>(wk, WQKV + 1024 * 1024, 1024, 1024);
  convT_kernel<<<dim3(32, 32), blk, 0, stream>>>(wv, WQKV + 2048 * 1024, 1024, 1024);
  convT_kernel<<<dim3(32, 32), blk, 0, stream>>>(wo, WO, 1024, 1024);
  convT_kernel<<<dim3(128, 32), blk, 0, stream>>>(w1, W1, 1024, 4096);
  convT_kernel<<<dim3(32, 128), blk, 0, stream>>>(w2, W2, 4096, 1024);
  // 2. LN1 -> H (bf16), all rows
  ln_bf16_kernel<<<16384, blk, 0, stream>>>(x, g1, be1, H);
  // 3. attention per batch
  for (int z = 0; z < 4; z++) {
    const long zo = (long)z * 4096 * 1024;
    // fused QKV: [4096,3072] = H_z @ WQKV^T + (bq|bk|bv)
    gemm_nt<EPI_QKV><<<dim3(24, 32), blk, 0, stream>>>(
        H + zo, WQKV, bq, bk, bv, nullptr, QKVb,
        4096, 3072, 1024, 1024, 1024, 3072, 1.0f);
    // V part -> Vt [1024,4096]
    transpose_bf16<<<dim3(32, 128), blk, 0, stream>>>(QKVb + 2048, Vt, 3072, 4096);
    // scores = Q K^T / 32
    gemm_nt<EPI_BF16><<<dim3(32, 32), blk, 0, stream>>>(
        QKVb, QKVb + 1024, nullptr, nullptr, nullptr, nullptr, P,
        4096, 4096, 1024, 3072, 3072, 4096, 1.0f / 32.0f);
    softmax_kernel<<<4096, blk, 0, stream>>>(P);
    // A_z = P @ V -> overwrite H_z (dead after QKV GEMM of this batch)
    gemm_nt<EPI_BF16><<<dim3(8, 32), blk, 0, stream>>>(
        P, Vt, nullptr, nullptr, nullptr, nullptr, H + zo,
        4096, 1024, 4096, 4096, 4096, 1024, 1.0f);
  }
  // 4. X1 = x + A @ WO^T + bo -> d_out (attention scratch dead)
  gemm_nt<EPI_F32RES><<<dim3(8, 128), blk, 0, stream>>>(
      H, WO, bo, nullptr, nullptr, x, OUT,
      16384, 1024, 1024, 1024, 1024, 1024, 1.0f);
  // 5. FFN in M-chunks of 4096 rows
  bf16* H2m = (bf16*)(ws + 0 * MB);   // over dead WQKV+WO (8 MB)
  bf16* Fm  = (bf16*)(ws + 24 * MB);  // over dead A (32 MB)
  for (int mc = 0; mc < 4; mc++) {
    const long ro = (long)mc * 4096 * 1024;
    ln_bf16_kernel<<<4096, blk, 0, stream>>>(OUT + ro, g2, be2, H2m);
    gemm_nt<EPI_GELU><<<dim3(32, 32), blk, 0, stream>>>(
        H2m, W1, b1, nullptr, nullptr, nullptr, Fm,
        4096, 4096, 1024, 1024, 1024, 4096, 1.0f);
    gemm_nt<EPI_F32RES><<<dim3(8, 32), blk, 0, stream>>>(
        Fm, W2, b2, nullptr, nullptr, OUT + ro, OUT + ro,
        4096, 1024, 4096, 4096, 4096, 1024, 1.0f);
  }
  (void)in_sizes; (void)n_in; (void)out_size; (void)ws_size;
}